// Round 2
// baseline (4866.320 us; speedup 1.0000x reference)
//
#include <hip/hip_runtime.h>
#include <math.h>

#define T_STEPS 8
#define F_DIM 64
#define H_DIM 64
#define C_DIM 16

__device__ __forceinline__ float sigmoidf_(float x) { return 1.f / (1.f + __expf(-x)); }

// ---------------- setup kernels ----------------
// edge_index arrives as int32 (harness converts integer inputs to int32).

__global__ void k_deg_cnt(const int* ei, int E, int N, int* deg, int* cnt) {
  int e = blockIdx.x * blockDim.x + threadIdx.x;
  if (e >= E) return;
  int s = ei[e];
  int d = ei[E + e];
  if ((unsigned)s < (unsigned)N) atomicAdd(&deg[s], 1);
  if ((unsigned)d < (unsigned)N) atomicAdd(&cnt[d], 1);
}

__global__ void k_dinv(const int* deg, float* dinv, int n) {
  int i = blockIdx.x * blockDim.x + threadIdx.x;
  if (i >= n) return;
  int d = deg[i];
  dinv[i] = d > 0 ? 1.0f / sqrtf((float)d) : 0.f;
}

__global__ void k_scan1(const int* cnt, int* incl, int* bsum, int n) {
  __shared__ int s[1024];
  int t = threadIdx.x;
  int i = blockIdx.x * 1024 + t;
  int v = (i < n) ? cnt[i] : 0;
  s[t] = v;
  __syncthreads();
  for (int off = 1; off < 1024; off <<= 1) {
    int add = (t >= off) ? s[t - off] : 0;
    __syncthreads();
    s[t] += add;
    __syncthreads();
  }
  if (i < n) incl[i] = s[t];
  if (t == 1023) bsum[blockIdx.x] = s[1023];
}

__global__ void k_scan2(const int* bsum, int* boff, int nb) {
  if (threadIdx.x == 0 && blockIdx.x == 0) {
    int run = 0;
    for (int b = 0; b < nb; ++b) { int v = bsum[b]; boff[b] = run; run += v; }
  }
}

__global__ void k_scan3(const int* incl, const int* cnt, const int* boff,
                        int* rp, int n, int E) {
  int i = blockIdx.x * 1024 + threadIdx.x;
  if (i >= n) return;
  int b = i >> 10;
  rp[i] = incl[i] - cnt[i] + boff[b];
  if (i == n - 1) rp[n] = incl[i] + boff[b];  // == E
}

__global__ void k_fill(const int* ei, int E, int N, const float* dinv,
                       const int* rp, int* fill, int* col, float* wv) {
  int e = blockIdx.x * blockDim.x + threadIdx.x;
  if (e >= E) return;
  int s = ei[e];
  int d = ei[E + e];
  if ((unsigned)s >= (unsigned)N || (unsigned)d >= (unsigned)N) return;
  int pos = atomicAdd(&fill[d], 1);
  int j = rp[d] + pos;
  col[j] = s;
  wv[j] = -dinv[s] * dinv[d];
}

// Pack weights into fused-K layouts:
// Wzr[256][128]: rows 0-63 [Whz0|Whr0], 64-127 [Whz1|Whr1], 128-191 [Wxz0|Wxr0], 192-255 [Wxz1|Wxr1]
// Wh2[256][64] : rows Whh0;Whh1;Wxh0;Wxh1
__global__ void k_pack(const float* Whz, const float* Whr, const float* Wxz, const float* Wxr,
                       const float* Whh, const float* Wxh,
                       const float* bhz, const float* bhr, const float* bxz, const float* bxr,
                       const float* bhh, const float* bxh,
                       float* Wzr, float* Wh2, float* bzr, float* bh) {
  int i = blockIdx.x * 256 + threadIdx.x;
  if (i < 256 * 128) {
    int r = i >> 7, o = i & 127;
    int half = r >> 6, kk = half & 1, ri = r & 63;
    const float* sz = half < 2 ? Whz : Wxz;
    const float* sr = half < 2 ? Whr : Wxr;
    const float* src = (o < 64) ? sz : sr;
    Wzr[i] = src[kk * 4096 + ri * 64 + (o & 63)];
  } else if (i < 256 * 128 + 256 * 64) {
    int q = i - 256 * 128;
    int r = q >> 6, o = q & 63;
    int half = r >> 6, kk = half & 1, ri = r & 63;
    const float* src = half < 2 ? Whh : Wxh;
    Wh2[q] = src[kk * 4096 + ri * 64 + o];
  } else if (i < 256 * 128 + 256 * 64 + 128) {
    int o = i - (256 * 128 + 256 * 64);
    bzr[o] = (o < 64) ? (bhz[o] + bxz[o]) : (bhr[o - 64] + bxr[o - 64]);
  } else if (i < 256 * 128 + 256 * 64 + 128 + 64) {
    int o = i - (256 * 128 + 256 * 64 + 128);
    bh[o] = bhh[o] + bxh[o];
  }
}

// ---------------- SpMV: y = L_tilde @ x (CSR by dst), one wave per row ----------------
__global__ __launch_bounds__(256) void k_spmv(const int* __restrict__ rp,
                                              const int* __restrict__ col,
                                              const float* __restrict__ wv,
                                              const float* __restrict__ x,
                                              float* __restrict__ y, int n) {
  int row = blockIdx.x * 4 + (threadIdx.x >> 6);
  if (row >= n) return;
  int lane = threadIdx.x & 63;
  int s = rp[row], e = rp[row + 1];
  float acc = 0.f;
  for (int j = s; j < e; ++j) {
    acc = fmaf(wv[j], x[(size_t)col[j] * 64 + lane], acc);
  }
  y[(size_t)row * 64 + lane] = acc;
}

// ---------------- fused K=256 GEMM (two passes of K=128), 64x64 tile ----------------
// EPI 0: ZR  (outw=128, grid.y=2): chunk0 -> z = sigmoid(acc+b); chunk1 -> hr = h * sigmoid(acc+b)
// EPI 1: H   (outw=64,  grid.y=1): ht = tanh(acc+b); h = z*h + (1-z)*ht
template <int EPI>
__global__ __launch_bounds__(256) void k_gemm(
    const float* __restrict__ A0, const float* __restrict__ B0,
    const float* __restrict__ A1, const float* __restrict__ B1,
    const float* __restrict__ Wp, int outw, const float* __restrict__ bias,
    const float* __restrict__ zin, const float* __restrict__ hin,
    float* __restrict__ o0, float* __restrict__ o1, int n) {
  __shared__ float Xs[128 * 64];  // [k][row], k-major
  __shared__ float Ws[128 * 64];  // [k][col]
  const int t = threadIdx.x;
  const int rq = t >> 4;   // 0..15 row-quad
  const int c4 = t & 15;   // 0..15 col-quad
  const int rowBase = blockIdx.x * 64;
  const int chunk = blockIdx.y;
  float acc[4][4] = {};

  for (int pass = 0; pass < 2; ++pass) {
    const float* A = pass ? A1 : A0;
    const float* B = pass ? B1 : B0;
    __syncthreads();
#pragma unroll
    for (int it = 0; it < 4; ++it) {
      int q = it * 256 + t;
      int k = q & 63, r4 = q >> 6;
      int gr = rowBase + 4 * r4;
      float4 va, vb;
      va.x = (gr + 0 < n) ? A[(size_t)(gr + 0) * 64 + k] : 0.f;
      va.y = (gr + 1 < n) ? A[(size_t)(gr + 1) * 64 + k] : 0.f;
      va.z = (gr + 2 < n) ? A[(size_t)(gr + 2) * 64 + k] : 0.f;
      va.w = (gr + 3 < n) ? A[(size_t)(gr + 3) * 64 + k] : 0.f;
      vb.x = (gr + 0 < n) ? B[(size_t)(gr + 0) * 64 + k] : 0.f;
      vb.y = (gr + 1 < n) ? B[(size_t)(gr + 1) * 64 + k] : 0.f;
      vb.z = (gr + 2 < n) ? B[(size_t)(gr + 2) * 64 + k] : 0.f;
      vb.w = (gr + 3 < n) ? B[(size_t)(gr + 3) * 64 + k] : 0.f;
      ((float4*)Xs)[k * 16 + r4] = va;
      ((float4*)Xs)[(64 + k) * 16 + r4] = vb;
    }
#pragma unroll
    for (int it = 0; it < 8; ++it) {
      int q = it * 256 + t;
      int k = q >> 4, cq = q & 15;
      ((float4*)Ws)[k * 16 + cq] =
          *(const float4*)(Wp + (size_t)(pass * 128 + k) * outw + chunk * 64 + 4 * cq);
    }
    __syncthreads();
#pragma unroll 4
    for (int k = 0; k < 128; ++k) {
      float4 xv = ((const float4*)Xs)[k * 16 + rq];
      float4 wv = ((const float4*)Ws)[k * 16 + c4];
      acc[0][0] = fmaf(xv.x, wv.x, acc[0][0]);
      acc[0][1] = fmaf(xv.x, wv.y, acc[0][1]);
      acc[0][2] = fmaf(xv.x, wv.z, acc[0][2]);
      acc[0][3] = fmaf(xv.x, wv.w, acc[0][3]);
      acc[1][0] = fmaf(xv.y, wv.x, acc[1][0]);
      acc[1][1] = fmaf(xv.y, wv.y, acc[1][1]);
      acc[1][2] = fmaf(xv.y, wv.z, acc[1][2]);
      acc[1][3] = fmaf(xv.y, wv.w, acc[1][3]);
      acc[2][0] = fmaf(xv.z, wv.x, acc[2][0]);
      acc[2][1] = fmaf(xv.z, wv.y, acc[2][1]);
      acc[2][2] = fmaf(xv.z, wv.z, acc[2][2]);
      acc[2][3] = fmaf(xv.z, wv.w, acc[2][3]);
      acc[3][0] = fmaf(xv.w, wv.x, acc[3][0]);
      acc[3][1] = fmaf(xv.w, wv.y, acc[3][1]);
      acc[3][2] = fmaf(xv.w, wv.z, acc[3][2]);
      acc[3][3] = fmaf(xv.w, wv.w, acc[3][3]);
    }
  }

  const int ccol = chunk * 64 + 4 * c4;
  float4 b4 = *(const float4*)(bias + ccol);
#pragma unroll
  for (int i = 0; i < 4; ++i) {
    int gr = rowBase + 4 * rq + i;
    if (gr >= n) break;
    if constexpr (EPI == 0) {
      float4 o;
      o.x = sigmoidf_(acc[i][0] + b4.x);
      o.y = sigmoidf_(acc[i][1] + b4.y);
      o.z = sigmoidf_(acc[i][2] + b4.z);
      o.w = sigmoidf_(acc[i][3] + b4.w);
      if (chunk == 0) {
        ((float4*)o0)[(size_t)gr * 16 + c4] = o;  // z
      } else {
        float4 h4 = ((const float4*)hin)[(size_t)gr * 16 + c4];
        o.x *= h4.x; o.y *= h4.y; o.z *= h4.z; o.w *= h4.w;
        ((float4*)o1)[(size_t)gr * 16 + c4] = o;  // hr = h * r
      }
    } else {
      float4 z4 = ((const float4*)zin)[(size_t)gr * 16 + c4];
      float4 h4 = ((const float4*)hin)[(size_t)gr * 16 + c4];
      float4 o;
      float ht;
      ht = tanhf(acc[i][0] + b4.x); o.x = z4.x * h4.x + (1.f - z4.x) * ht;
      ht = tanhf(acc[i][1] + b4.y); o.y = z4.y * h4.y + (1.f - z4.y) * ht;
      ht = tanhf(acc[i][2] + b4.z); o.z = z4.z * h4.z + (1.f - z4.z) * ht;
      ht = tanhf(acc[i][3] + b4.w); o.w = z4.w * h4.w + (1.f - z4.w) * ht;
      ((float4*)o0)[(size_t)gr * 16 + c4] = o;  // h in-place
    }
  }
}

// ---------------- final linear: out = h @ Wlin + blin ----------------
__global__ __launch_bounds__(256) void k_lin(const float* __restrict__ h,
                                             const float* __restrict__ Wlin,
                                             const float* __restrict__ blin,
                                             float* __restrict__ out, int n) {
  __shared__ float Wl[64 * 16];
  __shared__ float bl[16];
  int t = threadIdx.x;
#pragma unroll
  for (int it = 0; it < 4; ++it) Wl[it * 256 + t] = Wlin[it * 256 + t];
  if (t < 16) bl[t] = blin[t];
  __syncthreads();
  int r = blockIdx.x * 16 + (t >> 4);
  int c = t & 15;
  if (r >= n) return;
  const float* hp = h + (size_t)r * 64;
  float acc = bl[c];
#pragma unroll
  for (int k = 0; k < 64; ++k) acc = fmaf(hp[k], Wl[k * 16 + c], acc);
  out[(size_t)r * 16 + c] = acc;
}

extern "C" void kernel_launch(void* const* d_in, const int* in_sizes, int n_in,
                              void* d_out, int out_size, void* d_ws, size_t ws_size,
                              hipStream_t stream) {
  const float* Xseq = (const float*)d_in[0];
  const int* ei = (const int*)d_in[1];  // int32 per harness contract
  const float* Wxz = (const float*)d_in[2];
  const float* bxz = (const float*)d_in[3];
  const float* Whz = (const float*)d_in[4];
  const float* bhz = (const float*)d_in[5];
  const float* Wxr = (const float*)d_in[6];
  const float* bxr = (const float*)d_in[7];
  const float* Whr = (const float*)d_in[8];
  const float* bhr = (const float*)d_in[9];
  const float* Wxh = (const float*)d_in[10];
  const float* bxh = (const float*)d_in[11];
  const float* Whh = (const float*)d_in[12];
  const float* bhh = (const float*)d_in[13];
  const float* Wlin = (const float*)d_in[14];
  const float* blin = (const float*)d_in[15];
  float* out = (float*)d_out;

  const int N = in_sizes[0] / (T_STEPS * F_DIM);
  const int E = in_sizes[1] / 2;

  char* p = (char*)d_ws;
  auto alloc = [&](size_t bytes) {
    char* r = p;
    p += (bytes + 255) & ~(size_t)255;
    return r;
  };
  int* deg = (int*)alloc((size_t)N * 4);
  int* cnt = (int*)alloc((size_t)N * 4);
  int* incl = (int*)alloc((size_t)N * 4);
  int* fill = (int*)alloc((size_t)N * 4);
  int* bsum = (int*)alloc(512 * 4);
  int* boff = (int*)alloc(512 * 4);
  float* dinv = (float*)alloc((size_t)N * 4);
  int* rp = (int*)alloc((size_t)(N + 1) * 4);
  int* col = (int*)alloc((size_t)E * 4);
  float* wv = (float*)alloc((size_t)E * 4);
  float* Wzr = (float*)alloc(256 * 128 * 4);
  float* Wh2 = (float*)alloc(256 * 64 * 4);
  float* bzr = (float*)alloc(128 * 4);
  float* bh = (float*)alloc(64 * 4);
  float* h = (float*)alloc((size_t)N * 64 * 4);
  float* mvx = (float*)alloc((size_t)N * 64 * 4);
  float* mv2 = (float*)alloc((size_t)N * 64 * 4);
  float* z = (float*)alloc((size_t)N * 64 * 4);
  float* hr = (float*)alloc((size_t)N * 64 * 4);

  hipMemsetAsync(deg, 0, (size_t)N * 4, stream);
  hipMemsetAsync(cnt, 0, (size_t)N * 4, stream);
  hipMemsetAsync(fill, 0, (size_t)N * 4, stream);
  hipMemsetAsync(h, 0, (size_t)N * 64 * 4, stream);

  k_deg_cnt<<<(E + 255) / 256, 256, 0, stream>>>(ei, E, N, deg, cnt);
  k_dinv<<<(N + 255) / 256, 256, 0, stream>>>(deg, dinv, N);
  int nb = (N + 1023) / 1024;
  k_scan1<<<nb, 1024, 0, stream>>>(cnt, incl, bsum, N);
  k_scan2<<<1, 1, 0, stream>>>(bsum, boff, nb);
  k_scan3<<<nb, 1024, 0, stream>>>(incl, cnt, boff, rp, N, E);
  k_fill<<<(E + 255) / 256, 256, 0, stream>>>(ei, E, N, dinv, rp, fill, col, wv);
  k_pack<<<(49344 + 255) / 256, 256, 0, stream>>>(Whz, Whr, Wxz, Wxr, Whh, Wxh, bhz, bhr,
                                                  bxz, bxr, bhh, bxh, Wzr, Wh2, bzr, bh);

  int gb = (N + 63) / 64;
  for (int tt = 0; tt < T_STEPS; ++tt) {
    const float* xt = Xseq + (size_t)tt * N * F_DIM;
    k_spmv<<<(N + 3) / 4, 256, 0, stream>>>(rp, col, wv, xt, mvx, N);
    k_spmv<<<(N + 3) / 4, 256, 0, stream>>>(rp, col, wv, h, mv2, N);
    dim3 gzr(gb, 2);
    k_gemm<0><<<gzr, 256, 0, stream>>>(h, mv2, xt, mvx, Wzr, 128, bzr, nullptr, h, z, hr, N);
    k_spmv<<<(N + 3) / 4, 256, 0, stream>>>(rp, col, wv, hr, mv2, N);
    dim3 gh(gb, 1);
    k_gemm<1><<<gh, 256, 0, stream>>>(hr, mv2, xt, mvx, Wh2, 64, bh, z, h, h, nullptr, N);
  }
  k_lin<<<(N + 15) / 16, 256, 0, stream>>>(h, Wlin, blin, out, N);
}

// Round 3
// 2627.971 us; speedup vs baseline: 1.8517x; 1.8517x over previous
//
#include <hip/hip_runtime.h>
#include <math.h>

#define T_STEPS 8
#define F_DIM 64

using half8 = __attribute__((ext_vector_type(8))) _Float16;
using half4 = __attribute__((ext_vector_type(4))) _Float16;
using f32x4 = __attribute__((ext_vector_type(4))) float;

__device__ __forceinline__ float sigmoidf_(float x) { return 1.f / (1.f + __expf(-x)); }

// ---------------- setup kernels (edge_index arrives as int32) ----------------

__global__ void k_deg_cnt(const int* ei, int E, int N, int* deg, int* cnt) {
  int e = blockIdx.x * blockDim.x + threadIdx.x;
  if (e >= E) return;
  int s = ei[e];
  int d = ei[E + e];
  if ((unsigned)s < (unsigned)N) atomicAdd(&deg[s], 1);
  if ((unsigned)d < (unsigned)N) atomicAdd(&cnt[d], 1);
}

__global__ void k_dinv(const int* deg, float* dinv, int n) {
  int i = blockIdx.x * blockDim.x + threadIdx.x;
  if (i >= n) return;
  int d = deg[i];
  dinv[i] = d > 0 ? 1.0f / sqrtf((float)d) : 0.f;
}

__global__ void k_scan1(const int* cnt, int* incl, int* bsum, int n) {
  __shared__ int s[1024];
  int t = threadIdx.x;
  int i = blockIdx.x * 1024 + t;
  int v = (i < n) ? cnt[i] : 0;
  s[t] = v;
  __syncthreads();
  for (int off = 1; off < 1024; off <<= 1) {
    int add = (t >= off) ? s[t - off] : 0;
    __syncthreads();
    s[t] += add;
    __syncthreads();
  }
  if (i < n) incl[i] = s[t];
  if (t == 1023) bsum[blockIdx.x] = s[1023];
}

__global__ void k_scan2(const int* bsum, int* boff, int nb) {
  if (threadIdx.x == 0 && blockIdx.x == 0) {
    int run = 0;
    for (int b = 0; b < nb; ++b) { int v = bsum[b]; boff[b] = run; run += v; }
  }
}

__global__ void k_scan3(const int* incl, const int* cnt, const int* boff,
                        int* rp, int n, int E) {
  int i = blockIdx.x * 1024 + threadIdx.x;
  if (i >= n) return;
  int b = i >> 10;
  rp[i] = incl[i] - cnt[i] + boff[b];
  if (i == n - 1) rp[n] = incl[i] + boff[b];
}

__global__ void k_fill(const int* ei, int E, int N, const float* dinv,
                       const int* rp, int* fill, int* col, float* wv) {
  int e = blockIdx.x * blockDim.x + threadIdx.x;
  if (e >= E) return;
  int s = ei[e];
  int d = ei[E + e];
  if ((unsigned)s >= (unsigned)N || (unsigned)d >= (unsigned)N) return;
  int pos = atomicAdd(&fill[d], 1);
  int j = rp[d] + pos;
  col[j] = s;
  wv[j] = -dinv[s] * dinv[d];
}

// ---------------- weight pack: per-MFMA-fragment fp16 layout ----------------
// Fragment (c, kk): lane l holds B[k = kk*32 + (l>>4)*8 + i][col = c*16 + (l&15)],
// i = 0..7. Packed: W[((c*8+kk)*64 + l)*8 + i].
// ZR: 2 chunks (z, r) of 16384 halves; H: 1 chunk.
// K = [h*W0_h | h*W1_h | x*W0_x | x*W1_x] (m = K>>6, kidx = m&1, hpart = m<2).
__global__ void k_pack(const float* Whz, const float* Whr, const float* Wxz, const float* Wxr,
                       const float* Whh, const float* Wxh,
                       const float* bhz, const float* bhr, const float* bxz, const float* bxr,
                       const float* bhh, const float* bxh,
                       _Float16* Wzr, _Float16* Wh2, float* bzr, float* bhb) {
  int i = blockIdx.x * 256 + threadIdx.x;
  if (i < 49152) {
    int q, chunk;
    const float *srcH, *srcX;
    _Float16* dst;
    if (i < 32768) {
      chunk = i >> 14;
      q = i & 16383;
      srcH = chunk == 0 ? Whz : Whr;
      srcX = chunk == 0 ? Wxz : Wxr;
      dst = Wzr + i;
    } else {
      q = i - 32768;
      srcH = Whh;
      srcX = Wxh;
      dst = Wh2 + q;
    }
    int e = q & 7, lq = (q >> 3) & 63, kk = (q >> 9) & 7, c = (q >> 12) & 3;
    int K = kk * 32 + ((lq >> 4) << 3) + e;
    int colg = c * 16 + (lq & 15);
    int m = K >> 6, row = K & 63, kidx = m & 1;
    const float* src = (m < 2) ? srcH : srcX;
    *dst = (_Float16)src[kidx * 4096 + row * 64 + colg];
  } else if (i < 49152 + 128) {
    int o = i - 49152;
    bzr[o] = (o < 64) ? (bhz[o] + bxz[o]) : (bhr[o - 64] + bxr[o - 64]);
  } else if (i < 49152 + 128 + 64) {
    int o = i - (49152 + 128);
    bhb[o] = bhh[o] + bxh[o];
  }
}

// ---------------- convert X_seq fp32 [T][N][64] -> fp16 interleaved [N][T][64] ----
__global__ __launch_bounds__(256) void k_cvt_x(const float* __restrict__ X, _Float16* __restrict__ xh,
                                               int N, int total) {
  int i = blockIdx.x * 256 + threadIdx.x;
  if (i >= total) return;
  int per_t = N * 16;
  int t = i / per_t;
  int rem = i - t * per_t;
  int n = rem >> 4;
  int f4 = rem & 15;
  float4 v = *(const float4*)(X + (((size_t)t * N + n) << 6) + (f4 << 2));
  half4 o;
  o[0] = (_Float16)v.x; o[1] = (_Float16)v.y; o[2] = (_Float16)v.z; o[3] = (_Float16)v.w;
  *(half4*)(xh + ((size_t)n * (T_STEPS * 64)) + t * 64 + (f4 << 2)) = o;
}

// ---------------- batched SpMV over all 8 timesteps (x side) ----------------
__global__ __launch_bounds__(256) void k_spmv_x8(const int* __restrict__ rp,
                                                 const int* __restrict__ col,
                                                 const float* __restrict__ wv,
                                                 const _Float16* __restrict__ xh,
                                                 _Float16* __restrict__ y, int n) {
  int row = blockIdx.x * 4 + (threadIdx.x >> 6);
  if (row >= n) return;
  int lane = threadIdx.x & 63;
  int s = rp[row], e = rp[row + 1];
  float a[T_STEPS] = {};
  for (int j = s; j < e; ++j) {
    int c = col[j];
    float w = wv[j];
    const _Float16* xp = xh + ((size_t)c * (T_STEPS * 64)) + lane;
#pragma unroll
    for (int t = 0; t < T_STEPS; ++t) a[t] = fmaf(w, (float)xp[t * 64], a[t]);
  }
  _Float16* yp = y + ((size_t)row * (T_STEPS * 64)) + lane;
#pragma unroll
  for (int t = 0; t < T_STEPS; ++t) yp[t * 64] = (_Float16)a[t];
}

// ---------------- SpMV: y[N][64] fp16 = L_tilde @ x, one wave per row, ILP-2 ----
template <bool F32IN>
__global__ __launch_bounds__(256) void k_spmv(const int* __restrict__ rp,
                                              const int* __restrict__ col,
                                              const float* __restrict__ wv,
                                              const void* __restrict__ x, int xstride,
                                              _Float16* __restrict__ y, int n) {
  int row = blockIdx.x * 4 + (threadIdx.x >> 6);
  if (row >= n) return;
  int lane = threadIdx.x & 63;
  int s = rp[row], e = rp[row + 1];
  float acc = 0.f, acc2 = 0.f;
  int j = s;
  for (; j + 2 <= e; j += 2) {
    int c0 = col[j], c1 = col[j + 1];
    float w0 = wv[j], w1 = wv[j + 1];
    float v0, v1;
    if (F32IN) {
      v0 = ((const float*)x)[(size_t)c0 * xstride + lane];
      v1 = ((const float*)x)[(size_t)c1 * xstride + lane];
    } else {
      v0 = (float)((const _Float16*)x)[(size_t)c0 * xstride + lane];
      v1 = (float)((const _Float16*)x)[(size_t)c1 * xstride + lane];
    }
    acc = fmaf(w0, v0, acc);
    acc2 = fmaf(w1, v1, acc2);
  }
  if (j < e) {
    int c0 = col[j];
    float v0 = F32IN ? ((const float*)x)[(size_t)c0 * xstride + lane]
                     : (float)((const _Float16*)x)[(size_t)c0 * xstride + lane];
    acc = fmaf(wv[j], v0, acc);
  }
  y[(size_t)row * 64 + lane] = (_Float16)(acc + acc2);
}

// ---------------- MFMA fp16 GEMM, 64 rows x 64 cols per block, K=256 ----------------
// 4 waves in 2x2 (row-half x col-half). No LDS, no barriers. Weights in registers.
// mfma_f32_16x16x32_f16: A lane l -> row=l&15, k=(l>>4)*8+i ; B lane -> col=l&15, same k;
// D lane -> col=l&15, row=(l>>4)*4+reg.
// EPI 0 (ZR, grid.y=2): chunk0: zh = sigmoid(acc+b) ; chunk1: hrh = h * sigmoid(acc+b)
// EPI 1 (H): hn = z*h + (1-z)*tanh(acc+b); h (fp32) and hh (fp16) updated.
template <int EPI, bool XF>
__global__ __launch_bounds__(256) void k_gmfma(
    const _Float16* __restrict__ A0, const _Float16* __restrict__ A1,
    const void* __restrict__ A2, int s2, const _Float16* __restrict__ A3, int s3,
    const _Float16* __restrict__ Wpk, const float* __restrict__ bias,
    _Float16* __restrict__ zh, float* __restrict__ h, _Float16* __restrict__ hh,
    _Float16* __restrict__ hrh, int n) {
  const int t = threadIdx.x;
  const int l = t & 63;
  const int w = t >> 6;
  const int rh = w >> 1;  // row half (0/1)
  const int ch = w & 1;   // col half (0/1)
  const int rowBase = blockIdx.x * 64;
  const int chunk = (EPI == 0) ? blockIdx.y : 0;

  const _Float16* Wp = Wpk + (size_t)chunk * 16384;
  // preload 16 B-fragments (8 K-chunks x 2 col-tiles)
  half8 bf[8][2];
#pragma unroll
  for (int kk = 0; kk < 8; ++kk)
#pragma unroll
    for (int cc = 0; cc < 2; ++cc)
      bf[kk][cc] = *(const half8*)(Wp + ((((ch * 2 + cc) * 8 + kk) * 64 + l) << 3));

  const int row0 = rowBase + rh * 32 + (l & 15);
  const int row1 = row0 + 16;
  const bool r0ok = row0 < n, r1ok = row1 < n;

  f32x4 acc[2][2] = {};
#pragma unroll
  for (int kk = 0; kk < 8; ++kk) {
    const int m = kk >> 1;
    const int coloff = (kk & 1) * 32 + ((l >> 4) << 3);
    half8 a0{}, a1{};
    if (m == 2 && XF) {
      if (r0ok) {
        const float* p = (const float*)A2 + (size_t)row0 * s2 + coloff;
        float4 u = ((const float4*)p)[0], v = ((const float4*)p)[1];
        a0[0] = (_Float16)u.x; a0[1] = (_Float16)u.y; a0[2] = (_Float16)u.z; a0[3] = (_Float16)u.w;
        a0[4] = (_Float16)v.x; a0[5] = (_Float16)v.y; a0[6] = (_Float16)v.z; a0[7] = (_Float16)v.w;
      }
      if (r1ok) {
        const float* p = (const float*)A2 + (size_t)row1 * s2 + coloff;
        float4 u = ((const float4*)p)[0], v = ((const float4*)p)[1];
        a1[0] = (_Float16)u.x; a1[1] = (_Float16)u.y; a1[2] = (_Float16)u.z; a1[3] = (_Float16)u.w;
        a1[4] = (_Float16)v.x; a1[5] = (_Float16)v.y; a1[6] = (_Float16)v.z; a1[7] = (_Float16)v.w;
      }
    } else {
      const _Float16* base = (m == 0) ? A0 : (m == 1) ? A1 : (m == 2) ? (const _Float16*)A2 : A3;
      const int st = (m <= 1) ? 64 : (m == 2 ? s2 : s3);
      if (r0ok) a0 = *(const half8*)(base + (size_t)row0 * st + coloff);
      if (r1ok) a1 = *(const half8*)(base + (size_t)row1 * st + coloff);
    }
#pragma unroll
    for (int cc = 0; cc < 2; ++cc) {
      acc[0][cc] = __builtin_amdgcn_mfma_f32_16x16x32_f16(a0, bf[kk][cc], acc[0][cc], 0, 0, 0);
      acc[1][cc] = __builtin_amdgcn_mfma_f32_16x16x32_f16(a1, bf[kk][cc], acc[1][cc], 0, 0, 0);
    }
  }

#pragma unroll
  for (int rt = 0; rt < 2; ++rt)
#pragma unroll
    for (int cc = 0; cc < 2; ++cc) {
      const int colg = ch * 32 + cc * 16 + (l & 15);
      const float b = bias[chunk * 64 + colg];
#pragma unroll
      for (int reg = 0; reg < 4; ++reg) {
        const int row = rowBase + rh * 32 + rt * 16 + ((l >> 4) << 2) + reg;
        if (row >= n) continue;
        const float s = acc[rt][cc][reg] + b;
        const size_t idx = ((size_t)row << 6) + colg;
        if (EPI == 0) {
          const float g = sigmoidf_(s);
          if (chunk == 0) zh[idx] = (_Float16)g;
          else hrh[idx] = (_Float16)(h[idx] * g);
        } else {
          const float ht = tanhf(s);
          const float zz = (float)zh[idx];
          const float hn = zz * h[idx] + (1.f - zz) * ht;
          h[idx] = hn;
          hh[idx] = (_Float16)hn;
        }
      }
    }
}

// ---------------- final linear: out = h @ Wlin + blin ----------------
__global__ __launch_bounds__(256) void k_lin(const float* __restrict__ h,
                                             const float* __restrict__ Wlin,
                                             const float* __restrict__ blin,
                                             float* __restrict__ out, int n) {
  __shared__ float Wl[64 * 16];
  __shared__ float bl[16];
  int t = threadIdx.x;
#pragma unroll
  for (int it = 0; it < 4; ++it) Wl[it * 256 + t] = Wlin[it * 256 + t];
  if (t < 16) bl[t] = blin[t];
  __syncthreads();
  int r = blockIdx.x * 16 + (t >> 4);
  int c = t & 15;
  if (r >= n) return;
  const float* hp = h + (size_t)r * 64;
  float acc = bl[c];
#pragma unroll
  for (int k = 0; k < 64; ++k) acc = fmaf(hp[k], Wl[k * 16 + c], acc);
  out[(size_t)r * 16 + c] = acc;
}

extern "C" void kernel_launch(void* const* d_in, const int* in_sizes, int n_in,
                              void* d_out, int out_size, void* d_ws, size_t ws_size,
                              hipStream_t stream) {
  const float* Xseq = (const float*)d_in[0];
  const int* ei = (const int*)d_in[1];
  const float* Wxz = (const float*)d_in[2];
  const float* bxz = (const float*)d_in[3];
  const float* Whz = (const float*)d_in[4];
  const float* bhz = (const float*)d_in[5];
  const float* Wxr = (const float*)d_in[6];
  const float* bxr = (const float*)d_in[7];
  const float* Whr = (const float*)d_in[8];
  const float* bhr = (const float*)d_in[9];
  const float* Wxh = (const float*)d_in[10];
  const float* bxh = (const float*)d_in[11];
  const float* Whh = (const float*)d_in[12];
  const float* bhh = (const float*)d_in[13];
  const float* Wlin = (const float*)d_in[14];
  const float* blin = (const float*)d_in[15];
  float* out = (float*)d_out;

  const int N = in_sizes[0] / (T_STEPS * F_DIM);
  const int E = in_sizes[1] / 2;

  char* p = (char*)d_ws;
  size_t used = 0;
  auto alloc = [&](size_t bytes) {
    char* r = p;
    size_t a = (bytes + 255) & ~(size_t)255;
    p += a;
    used += a;
    return r;
  };
  int* deg = (int*)alloc((size_t)N * 4);
  int* cnt = (int*)alloc((size_t)N * 4);
  int* incl = (int*)alloc((size_t)N * 4);
  int* fill = (int*)alloc((size_t)N * 4);
  int* bsum = (int*)alloc(512 * 4);
  int* boff = (int*)alloc(512 * 4);
  float* dinv = (float*)alloc((size_t)N * 4);
  int* rp = (int*)alloc((size_t)(N + 1) * 4);
  int* col = (int*)alloc((size_t)E * 4);
  float* wv = (float*)alloc((size_t)E * 4);
  _Float16* Wzr = (_Float16*)alloc(32768 * 2);
  _Float16* Wh2 = (_Float16*)alloc(16384 * 2);
  float* bzr = (float*)alloc(128 * 4);
  float* bhb = (float*)alloc(64 * 4);
  float* h = (float*)alloc((size_t)N * 64 * 4);
  _Float16* hh = (_Float16*)alloc((size_t)N * 64 * 2);
  _Float16* mv2h = (_Float16*)alloc((size_t)N * 64 * 2);
  _Float16* hrh = (_Float16*)alloc((size_t)N * 64 * 2);
  _Float16* zh = (_Float16*)alloc((size_t)N * 64 * 2);

  // path decision: batched x (needs xh + mvx interleaved, 2 * N*512*2 bytes)
  size_t need_big = 2 * ((size_t)N * T_STEPS * 64 * 2 + 255);
  bool big = (used + need_big + (size_t)N * 64 * 2 + 4096) <= ws_size;
  _Float16 *xh_i = nullptr, *mvx_i = nullptr, *mvxh = nullptr;
  if (big) {
    xh_i = (_Float16*)alloc((size_t)N * T_STEPS * 64 * 2);
    mvx_i = (_Float16*)alloc((size_t)N * T_STEPS * 64 * 2);
  } else {
    mvxh = (_Float16*)alloc((size_t)N * 64 * 2);
  }

  hipMemsetAsync(deg, 0, (size_t)N * 4, stream);
  hipMemsetAsync(cnt, 0, (size_t)N * 4, stream);
  hipMemsetAsync(fill, 0, (size_t)N * 4, stream);
  hipMemsetAsync(h, 0, (size_t)N * 64 * 4, stream);
  hipMemsetAsync(hh, 0, (size_t)N * 64 * 2, stream);

  k_deg_cnt<<<(E + 255) / 256, 256, 0, stream>>>(ei, E, N, deg, cnt);
  k_dinv<<<(N + 255) / 256, 256, 0, stream>>>(deg, dinv, N);
  int nb = (N + 1023) / 1024;
  k_scan1<<<nb, 1024, 0, stream>>>(cnt, incl, bsum, N);
  k_scan2<<<1, 1, 0, stream>>>(bsum, boff, nb);
  k_scan3<<<nb, 1024, 0, stream>>>(incl, cnt, boff, rp, N, E);
  k_fill<<<(E + 255) / 256, 256, 0, stream>>>(ei, E, N, dinv, rp, fill, col, wv);
  k_pack<<<(49152 + 192 + 255) / 256, 256, 0, stream>>>(Whz, Whr, Wxz, Wxr, Whh, Wxh,
                                                        bhz, bhr, bxz, bxr, bhh, bxh,
                                                        Wzr, Wh2, bzr, bhb);

  if (big) {
    int total = T_STEPS * N * 16;
    k_cvt_x<<<(total + 255) / 256, 256, 0, stream>>>(Xseq, xh_i, N, total);
    k_spmv_x8<<<(N + 3) / 4, 256, 0, stream>>>(rp, col, wv, xh_i, mvx_i, N);
  }

  const int gb = (N + 63) / 64;
  for (int tt = 0; tt < T_STEPS; ++tt) {
    const float* xt = Xseq + (size_t)tt * N * F_DIM;
    const void* A2;
    const _Float16* A3;
    int s2, s3;
    if (big) {
      A2 = xh_i + tt * 64; s2 = T_STEPS * 64;
      A3 = mvx_i + tt * 64; s3 = T_STEPS * 64;
    } else {
      k_spmv<true><<<(N + 3) / 4, 256, 0, stream>>>(rp, col, wv, xt, 64, mvxh, N);
      A2 = xt; s2 = 64;
      A3 = mvxh; s3 = 64;
    }
    // mv(h)
    k_spmv<false><<<(N + 3) / 4, 256, 0, stream>>>(rp, col, wv, hh, 64, mv2h, N);
    // z and hr
    dim3 gzr(gb, 2);
    if (big)
      k_gmfma<0, false><<<gzr, 256, 0, stream>>>(hh, mv2h, A2, s2, A3, s3, Wzr, bzr,
                                                 zh, h, hh, hrh, N);
    else
      k_gmfma<0, true><<<gzr, 256, 0, stream>>>(hh, mv2h, A2, s2, A3, s3, Wzr, bzr,
                                                zh, h, hh, hrh, N);
    // mv(h*r)
    k_spmv<false><<<(N + 3) / 4, 256, 0, stream>>>(rp, col, wv, hrh, 64, mv2h, N);
    // h update
    dim3 gh(gb, 1);
    if (big)
      k_gmfma<1, false><<<gh, 256, 0, stream>>>(hrh, mv2h, A2, s2, A3, s3, Wh2, bhb,
                                                zh, h, hh, hrh, N);
    else
      k_gmfma<1, true><<<gh, 256, 0, stream>>>(hrh, mv2h, A2, s2, A3, s3, Wh2, bhb,
                                               zh, h, hh, hrh, N);
  }
  k_lin<<<(N + 15) / 16, 256, 0, stream>>>(h, Wlin, blin, out, N);
}